// Round 1
// baseline (1621.705 us; speedup 1.0000x reference)
//
#include <hip/hip_runtime.h>

#define NN 50000
#define NE 1600000
#define DD 64

// out = x * temp[0]; xbuf = x   (float4 over N*D/4)
__global__ __launch_bounds__(256) void init_kernel(const float4* __restrict__ x,
                                                   float4* __restrict__ out,
                                                   float4* __restrict__ xbuf,
                                                   const float* __restrict__ temp) {
    int i = blockIdx.x * blockDim.x + threadIdx.x;
    const int n4 = NN * DD / 4;
    if (i < n4) {
        float t0 = temp[0];
        float4 v = x[i];
        xbuf[i] = v;
        float4 o;
        o.x = v.x * t0; o.y = v.y * t0; o.z = v.z * t0; o.w = v.w * t0;
        out[i] = o;
    }
}

// h[n,o] = sum_d x[n,d] * Wl[o*64+d] + bl[o]
// block = 256 threads = 4 rows x 64 outputs; W^T staged in LDS (padded 65 stride)
__global__ __launch_bounds__(256) void gemm_kernel(const float* __restrict__ x,
                                                   const float* __restrict__ Wl,
                                                   const float* __restrict__ bl,
                                                   float* __restrict__ h) {
    __shared__ float WT[64 * 65];   // WT[d*65+o] = W[o*64+d]
    __shared__ float xs[4][64];
    __shared__ float bs[64];
    int t = threadIdx.x;
#pragma unroll
    for (int k = 0; k < 16; ++k) {
        int idx = t + k * 256;
        int o = idx >> 6, d = idx & 63;
        WT[d * 65 + o] = Wl[o * 64 + d];
    }
    if (t < 64) bs[t] = bl[t];
    int r = t >> 6, o = t & 63;
    int node = blockIdx.x * 4 + r;
    if (node < NN) xs[r][o] = x[node * 64 + o];
    __syncthreads();
    if (node < NN) {
        float acc = bs[o];
#pragma unroll
        for (int d = 0; d < 64; ++d)
            acc += xs[r][d] * WT[d * 65 + o];
        h[node * 64 + o] = acc;
    }
}

// one wave per edge; lane = feature. y[dst,d] += h[src,d] * w[e]
__global__ __launch_bounds__(256) void scatter_kernel(const float* __restrict__ h,
                                                      const float* __restrict__ w,
                                                      const int* __restrict__ src,
                                                      const int* __restrict__ dst,
                                                      float* __restrict__ y) {
    int e = blockIdx.x * 4 + (threadIdx.x >> 6);
    int lane = threadIdx.x & 63;
    if (e < NE) {
        int s = src[e];
        int d = dst[e];
        float we = w[e];
        float v = h[s * DD + lane] * we;
        atomicAdd(&y[d * DD + lane], v);
    }
}

// v = relu(y); xbuf = v; out += v * temp[layer+1]
__global__ __launch_bounds__(256) void epilogue_kernel(const float4* __restrict__ y,
                                                       float4* __restrict__ xbuf,
                                                       float4* __restrict__ out,
                                                       const float* __restrict__ temp,
                                                       int layer) {
    int i = blockIdx.x * blockDim.x + threadIdx.x;
    const int n4 = NN * DD / 4;
    if (i < n4) {
        float tk = temp[layer + 1];
        float4 v = y[i];
        v.x = fmaxf(v.x, 0.f); v.y = fmaxf(v.y, 0.f);
        v.z = fmaxf(v.z, 0.f); v.w = fmaxf(v.w, 0.f);
        xbuf[i] = v;
        float4 o = out[i];
        o.x += v.x * tk; o.y += v.y * tk;
        o.z += v.z * tk; o.w += v.w * tk;
        out[i] = o;
    }
}

extern "C" void kernel_launch(void* const* d_in, const int* in_sizes, int n_in,
                              void* d_out, int out_size, void* d_ws, size_t ws_size,
                              hipStream_t stream) {
    const float* x    = (const float*)d_in[0];
    const float* w    = (const float*)d_in[1];
    const float* W    = (const float*)d_in[2];
    const float* b    = (const float*)d_in[3];
    const float* temp = (const float*)d_in[4];
    const int*   src  = (const int*)d_in[5];
    const int*   dst  = (const int*)d_in[6];
    float* out = (float*)d_out;

    float* xbuf = (float*)d_ws;
    float* hbuf = xbuf + (size_t)NN * DD;
    float* ybuf = hbuf + (size_t)NN * DD;

    const int n4 = NN * DD / 4;
    init_kernel<<<(n4 + 255) / 256, 256, 0, stream>>>(
        (const float4*)x, (float4*)out, (float4*)xbuf, temp);

    for (int l = 0; l < 4; ++l) {
        gemm_kernel<<<(NN + 3) / 4, 256, 0, stream>>>(
            xbuf, W + (size_t)l * DD * DD, b + (size_t)l * DD, hbuf);
        hipMemsetAsync(ybuf, 0, (size_t)NN * DD * sizeof(float), stream);
        scatter_kernel<<<(NE + 3) / 4, 256, 0, stream>>>(hbuf, w, src, dst, ybuf);
        epilogue_kernel<<<(n4 + 255) / 256, 256, 0, stream>>>(
            (const float4*)ybuf, (float4*)xbuf, (float4*)out, temp, l);
    }
}

// Round 2
// 800.500 us; speedup vs baseline: 2.0259x; 2.0259x over previous
//
#include <hip/hip_runtime.h>

#define NN 50000
#define NE 1600000
#define DD 64
#define NB_SCAN 196   // ceil(NN/256)

// out = x*temp[0]; xbuf = x
__global__ __launch_bounds__(256) void init_kernel(const float4* __restrict__ x,
                                                   float4* __restrict__ out,
                                                   float4* __restrict__ xbuf,
                                                   const float* __restrict__ temp) {
    int i = blockIdx.x * blockDim.x + threadIdx.x;
    const int n4 = NN * DD / 4;
    if (i < n4) {
        float t0 = temp[0];
        float4 v = x[i];
        xbuf[i] = v;
        float4 o;
        o.x = v.x * t0; o.y = v.y * t0; o.z = v.z * t0; o.w = v.w * t0;
        out[i] = o;
    }
}

// deg[dst[e]]++
__global__ __launch_bounds__(256) void hist_kernel(const int* __restrict__ dst,
                                                   int* __restrict__ deg) {
    int i = blockIdx.x * blockDim.x + threadIdx.x;
    if (i < NE) atomicAdd(&deg[dst[i]], 1);
}

// per-256-chunk sums of deg
__global__ __launch_bounds__(256) void blocksum_kernel(const int* __restrict__ deg,
                                                       int* __restrict__ bsum) {
    __shared__ int sd[256];
    int t = threadIdx.x;
    int i = blockIdx.x * 256 + t;
    sd[t] = (i < NN) ? deg[i] : 0;
    __syncthreads();
    for (int s = 128; s > 0; s >>= 1) {
        if (t < s) sd[t] += sd[t + s];
        __syncthreads();
    }
    if (t == 0) bsum[blockIdx.x] = sd[0];
}

// exclusive scan of the NB_SCAN chunk sums (single block)
__global__ __launch_bounds__(256) void scantops_kernel(const int* __restrict__ bsum,
                                                       int* __restrict__ boff) {
    __shared__ int sd[256];
    int t = threadIdx.x;
    int v = (t < NB_SCAN) ? bsum[t] : 0;
    sd[t] = v;
    __syncthreads();
    for (int s = 1; s < 256; s <<= 1) {
        int add = (t >= s) ? sd[t - s] : 0;
        __syncthreads();
        sd[t] += add;
        __syncthreads();
    }
    boff[t] = sd[t] - v;   // exclusive
}

// off[i] = boff[chunk] + exclusive_scan_within_chunk(deg); off[NN] = NE
__global__ __launch_bounds__(256) void scanfinal_kernel(const int* __restrict__ deg,
                                                        const int* __restrict__ boff,
                                                        int* __restrict__ off) {
    __shared__ int sd[256];
    int t = threadIdx.x;
    int i = blockIdx.x * 256 + t;
    int v = (i < NN) ? deg[i] : 0;
    sd[t] = v;
    __syncthreads();
    for (int s = 1; s < 256; s <<= 1) {
        int add = (t >= s) ? sd[t - s] : 0;
        __syncthreads();
        sd[t] += add;
        __syncthreads();
    }
    if (i < NN) off[i] = boff[blockIdx.x] + sd[t] - v;
    if (blockIdx.x == 0 && t == 0) off[NN] = NE;
}

// bucket edges by dst: csr_src[pos]=src, csr_w[pos]=w
__global__ __launch_bounds__(256) void fill_kernel(const int* __restrict__ src,
                                                   const int* __restrict__ dst,
                                                   const float* __restrict__ w,
                                                   int* __restrict__ cur,
                                                   int* __restrict__ csr_src,
                                                   float* __restrict__ csr_w) {
    int i = blockIdx.x * blockDim.x + threadIdx.x;
    if (i < NE) {
        int d = dst[i];
        int pos = atomicAdd(&cur[d], 1);
        csr_src[pos] = src[i];
        csr_w[pos]  = w[i];
    }
}

// h = x @ W^T + b ; 16 nodes/block (W staged once, reused 16x), wave per node
__global__ __launch_bounds__(256) void gemm_kernel(const float* __restrict__ x,
                                                   const float* __restrict__ Wl,
                                                   const float* __restrict__ bl,
                                                   float* __restrict__ h) {
    __shared__ float WT[64 * 65];   // WT[d*65+o] = W[o*64+d]
    __shared__ float bs[64];
    int t = threadIdx.x;
#pragma unroll
    for (int k = 0; k < 16; ++k) {
        int idx = t + k * 256;
        int o = idx >> 6, d = idx & 63;
        WT[d * 65 + o] = Wl[o * 64 + d];
    }
    if (t < 64) bs[t] = bl[t];
    __syncthreads();
    int o = t & 63;
    int r = t >> 6;
#pragma unroll
    for (int p = 0; p < 4; ++p) {
        int node = blockIdx.x * 16 + p * 4 + r;
        if (node < NN) {
            const float* xr = x + (size_t)node * 64;
            float acc = bs[o];
#pragma unroll
            for (int d = 0; d < 64; ++d)
                acc += xr[d] * WT[d * 65 + o];   // xr[d] wave-uniform -> broadcast
            h[(size_t)node * 64 + o] = acc;
        }
    }
}

// pull: acc[node,lane] = sum_e w_e * h[src_e, lane]; fused relu + epilogue
__global__ __launch_bounds__(256) void pull_kernel(const float* __restrict__ h,
                                                   const int* __restrict__ csr_src,
                                                   const float* __restrict__ csr_w,
                                                   const int* __restrict__ off,
                                                   float* __restrict__ xbuf,
                                                   float* __restrict__ out,
                                                   const float* __restrict__ temp,
                                                   int layer) {
    int node = blockIdx.x * 4 + (threadIdx.x >> 6);
    int lane = threadIdx.x & 63;
    if (node >= NN) return;
    int beg = off[node];
    int end = off[node + 1];
    float acc = 0.f;
    for (int base = beg; base < end; base += 64) {
        int cnt = end - base;
        if (cnt > 64) cnt = 64;
        int s = 0; float wv = 0.f;
        if (lane < cnt) {
            s  = csr_src[base + lane];
            wv = csr_w[base + lane];
        }
        for (int j = 0; j < cnt; ++j) {
            int   sj = __shfl(s, j);
            float wj = __shfl(wv, j);
            acc += wj * h[(size_t)sj * 64 + lane];
        }
    }
    float v = fmaxf(acc, 0.f);
    int idx = node * 64 + lane;
    xbuf[idx] = v;
    out[idx] += v * temp[layer + 1];
}

extern "C" void kernel_launch(void* const* d_in, const int* in_sizes, int n_in,
                              void* d_out, int out_size, void* d_ws, size_t ws_size,
                              hipStream_t stream) {
    const float* x    = (const float*)d_in[0];
    const float* w    = (const float*)d_in[1];
    const float* W    = (const float*)d_in[2];
    const float* b    = (const float*)d_in[3];
    const float* temp = (const float*)d_in[4];
    const int*   src  = (const int*)d_in[5];
    const int*   dst  = (const int*)d_in[6];
    float* out = (float*)d_out;

    // workspace layout (~39 MB)
    float* xbuf    = (float*)d_ws;                 // NN*DD
    float* hbuf    = xbuf + (size_t)NN * DD;       // NN*DD
    float* csr_w   = hbuf + (size_t)NN * DD;       // NE
    int*   csr_src = (int*)(csr_w + NE);           // NE
    int*   deg     = csr_src + NE;                 // NN
    int*   off     = deg + NN;                     // NN+1
    int*   cur     = off + NN + 1;                 // NN+1
    int*   bsum    = cur + NN + 1;                 // 256
    int*   boff    = bsum + 256;                   // 256

    // ---- CSR build ----
    hipMemsetAsync(deg, 0, (size_t)NN * sizeof(int), stream);
    hist_kernel<<<(NE + 255) / 256, 256, 0, stream>>>(dst, deg);
    blocksum_kernel<<<NB_SCAN, 256, 0, stream>>>(deg, bsum);
    scantops_kernel<<<1, 256, 0, stream>>>(bsum, boff);
    scanfinal_kernel<<<NB_SCAN, 256, 0, stream>>>(deg, boff, off);
    hipMemcpyAsync(cur, off, (size_t)(NN + 1) * sizeof(int),
                   hipMemcpyDeviceToDevice, stream);
    fill_kernel<<<(NE + 255) / 256, 256, 0, stream>>>(src, dst, w, cur, csr_src, csr_w);

    // ---- init ----
    const int n4 = NN * DD / 4;
    init_kernel<<<(n4 + 255) / 256, 256, 0, stream>>>(
        (const float4*)x, (float4*)out, (float4*)xbuf, temp);

    // ---- layers ----
    for (int l = 0; l < 4; ++l) {
        gemm_kernel<<<(NN + 15) / 16, 256, 0, stream>>>(
            xbuf, W + (size_t)l * DD * DD, b + (size_t)l * DD, hbuf);
        pull_kernel<<<(NN + 3) / 4, 256, 0, stream>>>(
            hbuf, csr_src, csr_w, off, xbuf, out, temp, l);
    }
}

// Round 3
// 616.553 us; speedup vs baseline: 2.6303x; 1.2983x over previous
//
#include <hip/hip_runtime.h>

#define NN 50000
#define NE 1600000
#define DD 64
#define NB_SCAN 196   // ceil(NN/256)

// out = x*temp[0]; xbuf = x
__global__ __launch_bounds__(256) void init_kernel(const float4* __restrict__ x,
                                                   float4* __restrict__ out,
                                                   float4* __restrict__ xbuf,
                                                   const float* __restrict__ temp) {
    int i = blockIdx.x * blockDim.x + threadIdx.x;
    const int n4 = NN * DD / 4;
    if (i < n4) {
        float t0 = temp[0];
        float4 v = x[i];
        xbuf[i] = v;
        float4 o;
        o.x = v.x * t0; o.y = v.y * t0; o.z = v.z * t0; o.w = v.w * t0;
        out[i] = o;
    }
}

// deg[dst[e]]++
__global__ __launch_bounds__(256) void hist_kernel(const int* __restrict__ dst,
                                                   int* __restrict__ deg) {
    int i = blockIdx.x * blockDim.x + threadIdx.x;
    if (i < NE) atomicAdd(&deg[dst[i]], 1);
}

__global__ __launch_bounds__(256) void blocksum_kernel(const int* __restrict__ deg,
                                                       int* __restrict__ bsum) {
    __shared__ int sd[256];
    int t = threadIdx.x;
    int i = blockIdx.x * 256 + t;
    sd[t] = (i < NN) ? deg[i] : 0;
    __syncthreads();
    for (int s = 128; s > 0; s >>= 1) {
        if (t < s) sd[t] += sd[t + s];
        __syncthreads();
    }
    if (t == 0) bsum[blockIdx.x] = sd[0];
}

__global__ __launch_bounds__(256) void scantops_kernel(const int* __restrict__ bsum,
                                                       int* __restrict__ boff) {
    __shared__ int sd[256];
    int t = threadIdx.x;
    int v = (t < NB_SCAN) ? bsum[t] : 0;
    sd[t] = v;
    __syncthreads();
    for (int s = 1; s < 256; s <<= 1) {
        int add = (t >= s) ? sd[t - s] : 0;
        __syncthreads();
        sd[t] += add;
        __syncthreads();
    }
    boff[t] = sd[t] - v;   // exclusive
}

__global__ __launch_bounds__(256) void scanfinal_kernel(const int* __restrict__ deg,
                                                        const int* __restrict__ boff,
                                                        int* __restrict__ off) {
    __shared__ int sd[256];
    int t = threadIdx.x;
    int i = blockIdx.x * 256 + t;
    int v = (i < NN) ? deg[i] : 0;
    sd[t] = v;
    __syncthreads();
    for (int s = 1; s < 256; s <<= 1) {
        int add = (t >= s) ? sd[t - s] : 0;
        __syncthreads();
        sd[t] += add;
        __syncthreads();
    }
    if (i < NN) off[i] = boff[blockIdx.x] + sd[t] - v;
    if (blockIdx.x == 0 && t == 0) off[NN] = NE;
}

// bucket edges by dst, packed (src, w) -> one 8B scattered store per edge
__global__ __launch_bounds__(256) void fill_kernel(const int* __restrict__ src,
                                                   const int* __restrict__ dst,
                                                   const float* __restrict__ w,
                                                   int* __restrict__ cur,
                                                   int2* __restrict__ csr) {
    int i = blockIdx.x * blockDim.x + threadIdx.x;
    if (i < NE) {
        int d = dst[i];
        int pos = atomicAdd(&cur[d], 1);
        int2 e;
        e.x = src[i];
        e.y = __float_as_int(w[i]);
        csr[pos] = e;
    }
}

// h = x @ W^T + b ; 32 nodes/block (W staged once, reused 32x), wave per node
__global__ __launch_bounds__(256) void gemm_kernel(const float* __restrict__ x,
                                                   const float* __restrict__ Wl,
                                                   const float* __restrict__ bl,
                                                   float* __restrict__ h) {
    __shared__ float WT[64 * 65];   // WT[d*65+o] = W[o*64+d]
    __shared__ float bs[64];
    int t = threadIdx.x;
#pragma unroll
    for (int k = 0; k < 16; ++k) {
        int idx = t + k * 256;
        int o = idx >> 6, d = idx & 63;
        WT[d * 65 + o] = Wl[o * 64 + d];
    }
    if (t < 64) bs[t] = bl[t];
    __syncthreads();
    int o = t & 63;
    int r = t >> 6;
#pragma unroll
    for (int p = 0; p < 8; ++p) {
        int node = blockIdx.x * 32 + p * 4 + r;
        if (node < NN) {
            const float* xr = x + (size_t)node * 64;
            float acc = bs[o];
#pragma unroll
            for (int d = 0; d < 64; ++d)
                acc += xr[d] * WT[d * 65 + o];   // xr[d] wave-uniform -> broadcast
            h[(size_t)node * 64 + o] = acc;
        }
    }
}

// pull, quarter-wave float4: wave = 1 node; lane = (q=lane>>4, sub=lane&15).
// Each quarter processes a different edge; each lane holds 4 features (float4).
__global__ __launch_bounds__(256) void pull_kernel(const float4* __restrict__ h4,
                                                   const int2* __restrict__ csr,
                                                   const int* __restrict__ off,
                                                   float4* __restrict__ xbuf,
                                                   float4* __restrict__ out,
                                                   const float* __restrict__ temp,
                                                   int layer) {
    int node = blockIdx.x * 4 + (threadIdx.x >> 6);
    int lane = threadIdx.x & 63;
    if (node >= NN) return;
    int q = lane >> 4, sub = lane & 15;
    int beg = off[node];
    int end = off[node + 1];
    float4 acc = make_float4(0.f, 0.f, 0.f, 0.f);
    for (int base = beg; base < end; base += 64) {
        int cnt = end - base;
        if (cnt > 64) cnt = 64;
        int s = 0; float wv = 0.f;
        if (lane < cnt) {
            int2 e = csr[base + lane];
            s = e.x;
            wv = __int_as_float(e.y);
        }
        int cntp = (cnt + 3) & ~3;
        for (int j = 0; j < cntp; j += 4) {
            int lsrc = j + q;                       // per-lane source lane
            int   sj = __shfl(s, lsrc);
            float wj = __shfl(wv, lsrc);            // lanes >= cnt hold wv=0 -> no-op
            float4 hv = h4[(size_t)sj * 16 + sub];
            acc.x += wj * hv.x; acc.y += wj * hv.y;
            acc.z += wj * hv.z; acc.w += wj * hv.w;
        }
    }
    // reduce partial sums across the 4 quarters
#pragma unroll
    for (int m = 16; m < 64; m <<= 1) {
        acc.x += __shfl_xor(acc.x, m);
        acc.y += __shfl_xor(acc.y, m);
        acc.z += __shfl_xor(acc.z, m);
        acc.w += __shfl_xor(acc.w, m);
    }
    if (q == 0) {
        float tk = temp[layer + 1];
        float4 v;
        v.x = fmaxf(acc.x, 0.f); v.y = fmaxf(acc.y, 0.f);
        v.z = fmaxf(acc.z, 0.f); v.w = fmaxf(acc.w, 0.f);
        int idx = node * 16 + sub;
        xbuf[idx] = v;
        float4 o = out[idx];
        o.x += v.x * tk; o.y += v.y * tk;
        o.z += v.z * tk; o.w += v.w * tk;
        out[idx] = o;
    }
}

extern "C" void kernel_launch(void* const* d_in, const int* in_sizes, int n_in,
                              void* d_out, int out_size, void* d_ws, size_t ws_size,
                              hipStream_t stream) {
    const float* x    = (const float*)d_in[0];
    const float* w    = (const float*)d_in[1];
    const float* W    = (const float*)d_in[2];
    const float* b    = (const float*)d_in[3];
    const float* temp = (const float*)d_in[4];
    const int*   src  = (const int*)d_in[5];
    const int*   dst  = (const int*)d_in[6];
    float* out = (float*)d_out;

    // workspace layout
    float* xbuf = (float*)d_ws;                    // NN*DD
    float* hbuf = xbuf + (size_t)NN * DD;          // NN*DD
    int2*  csr  = (int2*)(hbuf + (size_t)NN * DD); // NE int2
    int*   deg  = (int*)(csr + NE);                // NN
    int*   off  = deg + NN;                        // NN+1
    int*   cur  = off + NN + 1;                    // NN+1
    int*   bsum = cur + NN + 1;                    // 256
    int*   boff = bsum + 256;                      // 256

    // ---- CSR build ----
    hipMemsetAsync(deg, 0, (size_t)NN * sizeof(int), stream);
    hist_kernel<<<(NE + 255) / 256, 256, 0, stream>>>(dst, deg);
    blocksum_kernel<<<NB_SCAN, 256, 0, stream>>>(deg, bsum);
    scantops_kernel<<<1, 256, 0, stream>>>(bsum, boff);
    scanfinal_kernel<<<NB_SCAN, 256, 0, stream>>>(deg, boff, off);
    hipMemcpyAsync(cur, off, (size_t)(NN + 1) * sizeof(int),
                   hipMemcpyDeviceToDevice, stream);
    fill_kernel<<<(NE + 255) / 256, 256, 0, stream>>>(src, dst, w, cur, csr);

    // ---- init ----
    const int n4 = NN * DD / 4;
    init_kernel<<<(n4 + 255) / 256, 256, 0, stream>>>(
        (const float4*)x, (float4*)out, (float4*)xbuf, temp);

    // ---- layers ----
    for (int l = 0; l < 4; ++l) {
        gemm_kernel<<<(NN + 31) / 32, 256, 0, stream>>>(
            xbuf, W + (size_t)l * DD * DD, b + (size_t)l * DD, hbuf);
        pull_kernel<<<(NN + 3) / 4, 256, 0, stream>>>(
            (const float4*)hbuf, csr, off, (float4*)xbuf, (float4*)out, temp, l);
    }
}